// Round 7
// baseline (180.560 us; speedup 1.0000x reference)
//
#include <hip/hip_runtime.h>
#include <hip/hip_fp16.h>

#define NNODES 4096
#define NEDGES 500000
#define NPAIRS 2000000
#define EDIM   16
#define LMAX   5

typedef int v4i __attribute__((ext_vector_type(4)));
typedef float v4f __attribute__((ext_vector_type(4)));

__device__ __forceinline__ v4i ntload4(const int* p) {
  return __builtin_nontemporal_load((const v4i*)p);
}
__device__ __forceinline__ void ntstore4(float* p, float x, float y, float z, float w) {
  v4f t = {x, y, z, w};
  __builtin_nontemporal_store(t, (v4f*)p);
}

// ---------------------------------------------------------------------------
// Kernel 0: dots[l*NEDGES + e] = fp16(dot(edge_attr[e,:], edge_weights[l,:]))
// ---------------------------------------------------------------------------
__global__ __launch_bounds__(256) void dots_kernel(
    const float* __restrict__ edge_attr,
    const float* __restrict__ ew,
    __half* __restrict__ dots) {
  __shared__ float w[LMAX * EDIM];
  int tid = threadIdx.x;
  if (tid < LMAX * EDIM) w[tid] = ew[tid];
  __syncthreads();

  int e0 = (blockIdx.x * 256 + tid) * 2;  // NEDGES even -> e0+1 always valid
  if (e0 >= NEDGES) return;

  const float4* ra = (const float4*)(edge_attr + (size_t)e0 * EDIM);
  float4 a0 = ra[0], a1 = ra[1], a2 = ra[2], a3 = ra[3];
  float4 b0 = ra[4], b1 = ra[5], b2 = ra[6], b3 = ra[7];  // edge e0+1
  float va[16] = {a0.x, a0.y, a0.z, a0.w, a1.x, a1.y, a1.z, a1.w,
                  a2.x, a2.y, a2.z, a2.w, a3.x, a3.y, a3.z, a3.w};
  float vb[16] = {b0.x, b0.y, b0.z, b0.w, b1.x, b1.y, b1.z, b1.w,
                  b2.x, b2.y, b2.z, b2.w, b3.x, b3.y, b3.z, b3.w};
#pragma unroll
  for (int l = 0; l < LMAX; ++l) {
    float da = 0.f, db = 0.f;
#pragma unroll
    for (int k = 0; k < EDIM; ++k) {
      da += va[k] * w[l * EDIM + k];
      db += vb[k] * w[l * EDIM + k];
    }
    __half2 h;
    h.x = __float2half(da);
    h.y = __float2half(db);
    *(__half2*)(dots + (size_t)l * NEDGES + e0) = h;  // e0 even -> 4B aligned
  }
}

// ---------------------------------------------------------------------------
// Fused mean + transpose, R7: zero-writes evicted to hipMemsetAsync.
// Lane-op accounting across R0..R6 (occupancy 31-73%, VGPR 16-32, three
// structures -> all ~57-65us) fits a per-CU lane-request limit, not BW or
// occupancy. Biggest removable term: 3.5M store-lanes / 56MB of zero-region
// writes carried INSIDE the gather kernel. The fill engine writes at 6.4TB/s
// (measured: 256MB in 41.7us), so: memset the whole output (~10.5us), then
// this kernel runs heavy blocks ONLY and writes just the 8MB valid strip.
// Body itself is R6 unchanged (single-variable experiment).
// ---------------------------------------------------------------------------
__device__ __forceinline__ float pair_mean(
    const __half* __restrict__ dots, int len,
    int i0, int i1, int i2, int i3, int i4) {
  len = min(max(len, 0), LMAX);
  // Address-select: invalid hops read dots[0] (hot line, lanes coalesce).
  int o0 = (len > 0) ? i0 : 0;
  int o1 = (len > 1) ? (1 * NEDGES + i1) : 0;
  int o2 = (len > 2) ? (2 * NEDGES + i2) : 0;
  int o3 = (len > 3) ? (3 * NEDGES + i3) : 0;
  int o4 = (len > 4) ? (4 * NEDGES + i4) : 0;
  float v0 = __half2float(dots[o0]);
  float v1 = __half2float(dots[o1]);
  float v2 = __half2float(dots[o2]);
  float v3 = __half2float(dots[o3]);
  float v4 = __half2float(dots[o4]);
  float s = (((len > 0) ? v0 : 0.f) + ((len > 1) ? v1 : 0.f)) +
            (((len > 2) ? v2 : 0.f) + ((len > 3) ? v3 : 0.f)) +
            ((len > 4) ? v4 : 0.f);
  return s / (float)max(len, 1);  // len==0 -> s==0 -> 0
}

#define NHEAVY 1024  // 512 tiles x 2 half-tiles (32 dst rows x 64 src cols)

__global__ __launch_bounds__(256, 4) void fused_mean_transpose(
    const int* __restrict__ path_idx,
    const int* __restrict__ path_lens,
    const __half* __restrict__ dots,
    float* __restrict__ out) {
  const int bid = blockIdx.x;  // 0..NHEAVY-1, consecutive -> XCD-uniform
  const int tid = threadIdx.x;  // 0..255

  // -------- heavy half-tile: 32 dst rows x 64 src cols
  const int tt = bid >> 1;                 // tile 0..511
  const int h  = bid & 1;                  // half 0..1
  const int dst0 = (tt & 7) * 64 + h * 32; // dst rows 0..511
  const int src0 = (tt >> 3) * 64;

  __shared__ float tile[64][33];  // [src_local][dst_local(32)+pad]

  {
    const int a = tid >> 4;   // dst row (chunk0) 0..15; chunk1 = a+16
    const int c = tid & 15;   // float4 group along src
    int p0 = (dst0 + a) * NNODES + src0 + 4 * c;   // multiple of 4
    int p1 = p0 + 16 * NNODES;
    // Branchless boundary: clamp to last valid chunk, zero via multiply.
    float valid0 = (p0 < NPAIRS) ? 1.f : 0.f;
    float valid1 = (p1 < NPAIRS) ? 1.f : 0.f;
    int pc0 = min(p0, NPAIRS - 4);  // NPAIRS%4==0 -> still chunk-aligned
    int pc1 = min(p1, NPAIRS - 4);

    // Issue ALL 12 streaming loads back-to-back (no control flow anywhere).
    const int* q0 = path_idx + (size_t)pc0 * LMAX;  // 16B aligned (pc%4==0)
    const int* q1 = path_idx + (size_t)pc1 * LMAX;
    v4i ln0 = ntload4(path_lens + pc0);
    v4i ln1 = ntload4(path_lens + pc1);
    v4i A0 = ntload4(q0);      v4i A1 = ntload4(q1);
    v4i B0 = ntload4(q0 + 4);  v4i B1 = ntload4(q1 + 4);
    v4i C0 = ntload4(q0 + 8);  v4i C1 = ntload4(q1 + 8);
    v4i D0 = ntload4(q0 + 12); v4i D1 = ntload4(q1 + 12);
    v4i E0 = ntload4(q0 + 16); v4i E1 = ntload4(q1 + 16);

    float4 v0, v1;
    v0.x = pair_mean(dots, ln0[0], A0[0], A0[1], A0[2], A0[3], B0[0]) * valid0;
    v0.y = pair_mean(dots, ln0[1], B0[1], B0[2], B0[3], C0[0], C0[1]) * valid0;
    v0.z = pair_mean(dots, ln0[2], C0[2], C0[3], D0[0], D0[1], D0[2]) * valid0;
    v0.w = pair_mean(dots, ln0[3], D0[3], E0[0], E0[1], E0[2], E0[3]) * valid0;
    v1.x = pair_mean(dots, ln1[0], A1[0], A1[1], A1[2], A1[3], B1[0]) * valid1;
    v1.y = pair_mean(dots, ln1[1], B1[1], B1[2], B1[3], C1[0], C1[1]) * valid1;
    v1.z = pair_mean(dots, ln1[2], C1[2], C1[3], D1[0], D1[1], D1[2]) * valid1;
    v1.w = pair_mean(dots, ln1[3], D1[3], E1[0], E1[1], E1[2], E1[3]) * valid1;

    // 2-way bank aliasing max on these scalar writes (free).
    tile[4 * c + 0][a] = v0.x;
    tile[4 * c + 1][a] = v0.y;
    tile[4 * c + 2][a] = v0.z;
    tile[4 * c + 3][a] = v0.w;
    tile[4 * c + 0][a + 16] = v1.x;
    tile[4 * c + 1][a + 16] = v1.y;
    tile[4 * c + 2][a + 16] = v1.z;
    tile[4 * c + 3][a + 16] = v1.w;
  }
  __syncthreads();
  {
    const int r  = tid >> 2;  // src row 0..63
    const int cc = tid & 3;   // float4 group along dst (0..3); +16 for second
    float x0 = tile[r][4 * cc + 0];
    float y0 = tile[r][4 * cc + 1];
    float z0 = tile[r][4 * cc + 2];
    float w0 = tile[r][4 * cc + 3];
    float x1 = tile[r][16 + 4 * cc + 0];
    float y1 = tile[r][16 + 4 * cc + 1];
    float z1 = tile[r][16 + 4 * cc + 2];
    float w1 = tile[r][16 + 4 * cc + 3];
    float* o = out + (size_t)(src0 + r) * NNODES + dst0;
    ntstore4(o + 4 * cc, x0, y0, z0, w0);
    ntstore4(o + 16 + 4 * cc, x1, y1, z1, w1);
  }
}

// ---------------------------------------------------------------------------
// Fallback (ws too small): memset + direct fp32 scatter.
// ---------------------------------------------------------------------------
__global__ __launch_bounds__(256) void scatter_kernel(
    const float* __restrict__ edge_attr,
    const float* __restrict__ ew,
    const int* __restrict__ path_idx,
    const int* __restrict__ path_lens,
    float* __restrict__ out) {
  __shared__ float w[LMAX * EDIM];
  if (threadIdx.x < LMAX * EDIM) w[threadIdx.x] = ew[threadIdx.x];
  __syncthreads();

  int p = blockIdx.x * 256 + threadIdx.x;
  if (p >= NPAIRS) return;

  int len = path_lens[p];
  len = min(max(len, 0), LMAX);

  const int* row = path_idx + (size_t)p * LMAX;
  float s = 0.f;
  for (int l = 0; l < len; ++l) {
    int idx = row[l];
    const float4* r = (const float4*)(edge_attr + (size_t)idx * EDIM);
    float4 a0 = r[0], a1 = r[1], a2 = r[2], a3 = r[3];
    const float* wl = &w[l * EDIM];
    s += a0.x * wl[0] + a0.y * wl[1] + a0.z * wl[2] + a0.w * wl[3] +
         a1.x * wl[4] + a1.y * wl[5] + a1.z * wl[6] + a1.w * wl[7] +
         a2.x * wl[8] + a2.y * wl[9] + a2.z * wl[10] + a2.w * wl[11] +
         a3.x * wl[12] + a3.y * wl[13] + a3.z * wl[14] + a3.w * wl[15];
  }
  float m = (len > 0) ? (s / (float)len) : 0.f;
  int src = p & (NNODES - 1);
  int dst = p >> 12;
  out[(size_t)src * NNODES + dst] = m;
}

extern "C" void kernel_launch(void* const* d_in, const int* in_sizes, int n_in,
                              void* d_out, int out_size, void* d_ws, size_t ws_size,
                              hipStream_t stream) {
  // setup_inputs order: x, edge_attr, edge_weights, path_idx, path_lens, pair_id
  const float* edge_attr = (const float*)d_in[1];
  const float* edge_w    = (const float*)d_in[2];
  const int*   path_idx  = (const int*)d_in[3];
  const int*   path_lens = (const int*)d_in[4];
  float* out = (float*)d_out;

  // ws layout: dots fp16 only (5MB).
  const size_t need = (size_t)LMAX * NEDGES * sizeof(__half);

  if (ws_size >= need) {
    __half* dots = (__half*)d_ws;

    // Zero the whole output at fill-engine rate (~6.4 TB/s measured);
    // the heavy kernel then writes only the 8MB valid strip.
    hipMemsetAsync(d_out, 0, (size_t)NNODES * NNODES * sizeof(float), stream);
    dots_kernel<<<(NEDGES / 2 + 255) / 256, 256, 0, stream>>>(edge_attr, edge_w, dots);
    fused_mean_transpose<<<NHEAVY, 256, 0, stream>>>(path_idx, path_lens, dots, out);
  } else {
    hipMemsetAsync(d_out, 0, (size_t)out_size * sizeof(float), stream);
    scatter_kernel<<<(NPAIRS + 255) / 256, 256, 0, stream>>>(
        edge_attr, edge_w, path_idx, path_lens, out);
  }
}

// Round 8
// 180.290 us; speedup vs baseline: 1.0015x; 1.0015x over previous
//
#include <hip/hip_runtime.h>
#include <hip/hip_fp16.h>

#define NNODES 4096
#define NEDGES 500000
#define NPAIRS 2000000
#define EDIM   16
#define LMAX   5

typedef int v4i __attribute__((ext_vector_type(4)));
typedef float v4f __attribute__((ext_vector_type(4)));

__device__ __forceinline__ v4i ntload4(const int* p) {
  return __builtin_nontemporal_load((const v4i*)p);
}
__device__ __forceinline__ void ntstore4(float* p, float x, float y, float z, float w) {
  v4f t = {x, y, z, w};
  __builtin_nontemporal_store(t, (v4f*)p);
}

// ---------------------------------------------------------------------------
// Kernel 0: dots[l*NEDGES + e] = fp16(dot(edge_attr[e,:], edge_weights[l,:]))
// ---------------------------------------------------------------------------
__global__ __launch_bounds__(256) void dots_kernel(
    const float* __restrict__ edge_attr,
    const float* __restrict__ ew,
    __half* __restrict__ dots) {
  __shared__ float w[LMAX * EDIM];
  int tid = threadIdx.x;
  if (tid < LMAX * EDIM) w[tid] = ew[tid];
  __syncthreads();

  int e0 = (blockIdx.x * 256 + tid) * 2;  // NEDGES even -> e0+1 always valid
  if (e0 >= NEDGES) return;

  const float4* ra = (const float4*)(edge_attr + (size_t)e0 * EDIM);
  float4 a0 = ra[0], a1 = ra[1], a2 = ra[2], a3 = ra[3];
  float4 b0 = ra[4], b1 = ra[5], b2 = ra[6], b3 = ra[7];  // edge e0+1
  float va[16] = {a0.x, a0.y, a0.z, a0.w, a1.x, a1.y, a1.z, a1.w,
                  a2.x, a2.y, a2.z, a2.w, a3.x, a3.y, a3.z, a3.w};
  float vb[16] = {b0.x, b0.y, b0.z, b0.w, b1.x, b1.y, b1.z, b1.w,
                  b2.x, b2.y, b2.z, b2.w, b3.x, b3.y, b3.z, b3.w};
#pragma unroll
  for (int l = 0; l < LMAX; ++l) {
    float da = 0.f, db = 0.f;
#pragma unroll
    for (int k = 0; k < EDIM; ++k) {
      da += va[k] * w[l * EDIM + k];
      db += vb[k] * w[l * EDIM + k];
    }
    __half2 h;
    h.x = __float2half(da);
    h.y = __float2half(db);
    *(__half2*)(dots + (size_t)l * NEDGES + e0) = h;  // e0 even -> 4B aligned
  }
}

// ---------------------------------------------------------------------------
// Fused mean + transpose, R8: sched_barrier-fenced 3-phase body.
// R7 decomposition: FETCH 87.5MB = 48MB mandatory streams + ~39.5MB gather
// misses (= 8 XCDs x 5MB full table replication -> fetch at its floor);
// WRITE 10MB at floor. 98MB in 48us = 2TB/s => 3.2x off the BW roofline,
// VALUBusy 5.5% -> outstanding-limited. VGPR_Count has been pinned at 16-32
// for 4 rounds: the RP-minimizing scheduler sinks every load to its use
// (~2-3 outstanding/wave; 16 waves/CU x 3 x 64B / 600cy = 2.6TB/s = the
// invariant rate). Fix: hard compile-time fences.
//   Phase 1: issue 12 stream loads (chunk0's six FIRST -> its gathers wait
//            only vmcnt(6)).            sched_barrier(0)
//   Phase 2: compute 40 addrs, issue 40 gather loads into named __half regs.
//            sched_barrier(0)
//   Phase 3: mask/convert/sum, LDS, transpose, NT store.
// ---------------------------------------------------------------------------
struct G5 { __half h0, h1, h2, h3, h4; };

__device__ __forceinline__ void gather5(const __half* __restrict__ dots, int len,
                                        int i0, int i1, int i2, int i3, int i4,
                                        G5& g) {
  len = min(max(len, 0), LMAX);
  // Address-select (invalid hops -> dots[0], one hot line); loads unconditional.
  int o0 = (len > 0) ? i0 : 0;
  int o1 = (len > 1) ? (1 * NEDGES + i1) : 0;
  int o2 = (len > 2) ? (2 * NEDGES + i2) : 0;
  int o3 = (len > 3) ? (3 * NEDGES + i3) : 0;
  int o4 = (len > 4) ? (4 * NEDGES + i4) : 0;
  g.h0 = dots[o0];
  g.h1 = dots[o1];
  g.h2 = dots[o2];
  g.h3 = dots[o3];
  g.h4 = dots[o4];
}

__device__ __forceinline__ float sum5(int len, const G5& g) {
  len = min(max(len, 0), LMAX);
  float s = (((len > 0) ? __half2float(g.h0) : 0.f) +
             ((len > 1) ? __half2float(g.h1) : 0.f)) +
            (((len > 2) ? __half2float(g.h2) : 0.f) +
             ((len > 3) ? __half2float(g.h3) : 0.f)) +
            ((len > 4) ? __half2float(g.h4) : 0.f);
  return s / (float)max(len, 1);  // len==0 -> s==0 -> 0
}

#define NHEAVY 1024  // 512 tiles x 2 half-tiles (32 dst rows x 64 src cols)

__global__ __launch_bounds__(256, 4) void fused_mean_transpose(
    const int* __restrict__ path_idx,
    const int* __restrict__ path_lens,
    const __half* __restrict__ dots,
    float* __restrict__ out) {
  const int bid = blockIdx.x;   // 0..NHEAVY-1, consecutive -> XCD-uniform
  const int tid = threadIdx.x;  // 0..255

  const int tt = bid >> 1;                 // tile 0..511
  const int h  = bid & 1;                  // half 0..1
  const int dst0 = (tt & 7) * 64 + h * 32; // dst rows 0..511
  const int src0 = (tt >> 3) * 64;

  __shared__ float tile[64][33];  // [src_local][dst_local(32)+pad]

  {
    const int a = tid >> 4;   // dst row (chunk0) 0..15; chunk1 = a+16
    const int c = tid & 15;   // float4 group along src
    int p0 = (dst0 + a) * NNODES + src0 + 4 * c;   // multiple of 4
    int p1 = p0 + 16 * NNODES;
    float valid0 = (p0 < NPAIRS) ? 1.f : 0.f;
    float valid1 = (p1 < NPAIRS) ? 1.f : 0.f;
    int pc0 = min(p0, NPAIRS - 4);  // NPAIRS%4==0 -> still chunk-aligned
    int pc1 = min(p1, NPAIRS - 4);

    // ---- Phase 1: issue all 12 stream loads (chunk0 first) --------------
    const int* q0 = path_idx + (size_t)pc0 * LMAX;  // 16B aligned (pc%4==0)
    const int* q1 = path_idx + (size_t)pc1 * LMAX;
    v4i ln0 = ntload4(path_lens + pc0);
    v4i A0 = ntload4(q0);
    v4i B0 = ntload4(q0 + 4);
    v4i C0 = ntload4(q0 + 8);
    v4i D0 = ntload4(q0 + 12);
    v4i E0 = ntload4(q0 + 16);
    v4i ln1 = ntload4(path_lens + pc1);
    v4i A1 = ntload4(q1);
    v4i B1 = ntload4(q1 + 4);
    v4i C1 = ntload4(q1 + 8);
    v4i D1 = ntload4(q1 + 12);
    v4i E1 = ntload4(q1 + 16);
    __builtin_amdgcn_sched_barrier(0);  // no load sinks below this point

    // ---- Phase 2: issue all 40 gathers into named regs ------------------
    G5 ga, gb, gc, gd, ge, gf, gg, gh;
    gather5(dots, ln0[0], A0[0], A0[1], A0[2], A0[3], B0[0], ga);
    gather5(dots, ln0[1], B0[1], B0[2], B0[3], C0[0], C0[1], gb);
    gather5(dots, ln0[2], C0[2], C0[3], D0[0], D0[1], D0[2], gc);
    gather5(dots, ln0[3], D0[3], E0[0], E0[1], E0[2], E0[3], gd);
    gather5(dots, ln1[0], A1[0], A1[1], A1[2], A1[3], B1[0], ge);
    gather5(dots, ln1[1], B1[1], B1[2], B1[3], C1[0], C1[1], gf);
    gather5(dots, ln1[2], C1[2], C1[3], D1[0], D1[1], D1[2], gg);
    gather5(dots, ln1[3], D1[3], E1[0], E1[1], E1[2], E1[3], gh);
    __builtin_amdgcn_sched_barrier(0);  // all 40 gathers issued before any use

    // ---- Phase 3: mask/convert/sum, LDS ---------------------------------
    float4 v0, v1;
    v0.x = sum5(ln0[0], ga) * valid0;
    v0.y = sum5(ln0[1], gb) * valid0;
    v0.z = sum5(ln0[2], gc) * valid0;
    v0.w = sum5(ln0[3], gd) * valid0;
    v1.x = sum5(ln1[0], ge) * valid1;
    v1.y = sum5(ln1[1], gf) * valid1;
    v1.z = sum5(ln1[2], gg) * valid1;
    v1.w = sum5(ln1[3], gh) * valid1;

    // 2-way bank aliasing max on these scalar writes (free).
    tile[4 * c + 0][a] = v0.x;
    tile[4 * c + 1][a] = v0.y;
    tile[4 * c + 2][a] = v0.z;
    tile[4 * c + 3][a] = v0.w;
    tile[4 * c + 0][a + 16] = v1.x;
    tile[4 * c + 1][a + 16] = v1.y;
    tile[4 * c + 2][a + 16] = v1.z;
    tile[4 * c + 3][a + 16] = v1.w;
  }
  __syncthreads();
  {
    const int r  = tid >> 2;  // src row 0..63
    const int cc = tid & 3;   // float4 group along dst (0..3); +16 for second
    float x0 = tile[r][4 * cc + 0];
    float y0 = tile[r][4 * cc + 1];
    float z0 = tile[r][4 * cc + 2];
    float w0 = tile[r][4 * cc + 3];
    float x1 = tile[r][16 + 4 * cc + 0];
    float y1 = tile[r][16 + 4 * cc + 1];
    float z1 = tile[r][16 + 4 * cc + 2];
    float w1 = tile[r][16 + 4 * cc + 3];
    float* o = out + (size_t)(src0 + r) * NNODES + dst0;
    ntstore4(o + 4 * cc, x0, y0, z0, w0);
    ntstore4(o + 16 + 4 * cc, x1, y1, z1, w1);
  }
}

// ---------------------------------------------------------------------------
// Fallback (ws too small): memset + direct fp32 scatter.
// ---------------------------------------------------------------------------
__global__ __launch_bounds__(256) void scatter_kernel(
    const float* __restrict__ edge_attr,
    const float* __restrict__ ew,
    const int* __restrict__ path_idx,
    const int* __restrict__ path_lens,
    float* __restrict__ out) {
  __shared__ float w[LMAX * EDIM];
  if (threadIdx.x < LMAX * EDIM) w[threadIdx.x] = ew[threadIdx.x];
  __syncthreads();

  int p = blockIdx.x * 256 + threadIdx.x;
  if (p >= NPAIRS) return;

  int len = path_lens[p];
  len = min(max(len, 0), LMAX);

  const int* row = path_idx + (size_t)p * LMAX;
  float s = 0.f;
  for (int l = 0; l < len; ++l) {
    int idx = row[l];
    const float4* r = (const float4*)(edge_attr + (size_t)idx * EDIM);
    float4 a0 = r[0], a1 = r[1], a2 = r[2], a3 = r[3];
    const float* wl = &w[l * EDIM];
    s += a0.x * wl[0] + a0.y * wl[1] + a0.z * wl[2] + a0.w * wl[3] +
         a1.x * wl[4] + a1.y * wl[5] + a1.z * wl[6] + a1.w * wl[7] +
         a2.x * wl[8] + a2.y * wl[9] + a2.z * wl[10] + a2.w * wl[11] +
         a3.x * wl[12] + a3.y * wl[13] + a3.z * wl[14] + a3.w * wl[15];
  }
  float m = (len > 0) ? (s / (float)len) : 0.f;
  int src = p & (NNODES - 1);
  int dst = p >> 12;
  out[(size_t)src * NNODES + dst] = m;
}

extern "C" void kernel_launch(void* const* d_in, const int* in_sizes, int n_in,
                              void* d_out, int out_size, void* d_ws, size_t ws_size,
                              hipStream_t stream) {
  // setup_inputs order: x, edge_attr, edge_weights, path_idx, path_lens, pair_id
  const float* edge_attr = (const float*)d_in[1];
  const float* edge_w    = (const float*)d_in[2];
  const int*   path_idx  = (const int*)d_in[3];
  const int*   path_lens = (const int*)d_in[4];
  float* out = (float*)d_out;

  // ws layout: dots fp16 only (5MB).
  const size_t need = (size_t)LMAX * NEDGES * sizeof(__half);

  if (ws_size >= need) {
    __half* dots = (__half*)d_ws;

    // Zero the whole output at fill-engine rate; the heavy kernel writes
    // only the 8MB valid strip.
    hipMemsetAsync(d_out, 0, (size_t)NNODES * NNODES * sizeof(float), stream);
    dots_kernel<<<(NEDGES / 2 + 255) / 256, 256, 0, stream>>>(edge_attr, edge_w, dots);
    fused_mean_transpose<<<NHEAVY, 256, 0, stream>>>(path_idx, path_lens, dots, out);
  } else {
    hipMemsetAsync(d_out, 0, (size_t)out_size * sizeof(float), stream);
    scatter_kernel<<<(NPAIRS + 255) / 256, 256, 0, stream>>>(
        edge_attr, edge_w, path_idx, path_lens, out);
  }
}

// Round 9
// 174.751 us; speedup vs baseline: 1.0332x; 1.0317x over previous
//
#include <hip/hip_runtime.h>
#include <hip/hip_fp16.h>

#define NNODES 4096
#define NEDGES 500000
#define NPAIRS 2000000
#define EDIM   16
#define LMAX   5

typedef int v4i __attribute__((ext_vector_type(4)));
typedef float v4f __attribute__((ext_vector_type(4)));

__device__ __forceinline__ v4i ntload4(const int* p) {
  return __builtin_nontemporal_load((const v4i*)p);
}
__device__ __forceinline__ void ntstore4(float* p, float x, float y, float z, float w) {
  v4f t = {x, y, z, w};
  __builtin_nontemporal_store(t, (v4f*)p);
}

// Destination-free async gather: per-lane GLOBAL address, LDS dest =
// wave-uniform base + lane*4. No VGPR result => compiler cannot sink it;
// vmcnt tracks it => 40+ outstanding per wave.
#define GLL(gp, lp) __builtin_amdgcn_global_load_lds(                      \
    (const __attribute__((address_space(1))) uint32_t*)(gp),               \
    (__attribute__((address_space(3))) uint32_t*)(lp), 4, 0, 0)

// ---------------------------------------------------------------------------
// Prep kernel: zero the whole 64MB output (store blocks) AND build the fp16
// dots table (compute blocks) in ONE dispatch -- replaces the serial
// hipMemsetAsync(10.5us) + dots_kernel(~8us) chain with ~max of the two.
// ---------------------------------------------------------------------------
#define DBLOCKS ((NEDGES / 2 + 255) / 256)   // 977 dots blocks
#define ZBLOCKS 16384                        // 64MB / (256 thr * 16B)

__global__ __launch_bounds__(256) void prep_kernel(
    const float* __restrict__ edge_attr,
    const float* __restrict__ ew,
    __half* __restrict__ dots,
    float* __restrict__ out) {
  __shared__ float w[LMAX * EDIM];
  const int tid = threadIdx.x, bid = blockIdx.x;

  if (bid >= DBLOCKS) {  // ---- zero block: one float4 per thread
    int z = bid - DBLOCKS;  // 0..ZBLOCKS-1
    ntstore4(out + ((size_t)z * 256 + tid) * 4, 0.f, 0.f, 0.f, 0.f);
    return;
  }

  // ---- dots block
  if (tid < LMAX * EDIM) w[tid] = ew[tid];
  __syncthreads();

  int e0 = (bid * 256 + tid) * 2;  // NEDGES even -> e0+1 always valid
  if (e0 >= NEDGES) return;

  const float4* ra = (const float4*)(edge_attr + (size_t)e0 * EDIM);
  float4 a0 = ra[0], a1 = ra[1], a2 = ra[2], a3 = ra[3];
  float4 b0 = ra[4], b1 = ra[5], b2 = ra[6], b3 = ra[7];  // edge e0+1
  float va[16] = {a0.x, a0.y, a0.z, a0.w, a1.x, a1.y, a1.z, a1.w,
                  a2.x, a2.y, a2.z, a2.w, a3.x, a3.y, a3.z, a3.w};
  float vb[16] = {b0.x, b0.y, b0.z, b0.w, b1.x, b1.y, b1.z, b1.w,
                  b2.x, b2.y, b2.z, b2.w, b3.x, b3.y, b3.z, b3.w};
#pragma unroll
  for (int l = 0; l < LMAX; ++l) {
    float da = 0.f, db = 0.f;
#pragma unroll
    for (int k = 0; k < EDIM; ++k) {
      da += va[k] * w[l * EDIM + k];
      db += vb[k] * w[l * EDIM + k];
    }
    __half2 h;
    h.x = __float2half(da);
    h.y = __float2half(db);
    *(__half2*)(dots + (size_t)l * NEDGES + e0) = h;  // e0 even -> 4B aligned
  }
}

// ---------------------------------------------------------------------------
// Fused mean + transpose, R9: async LDS-destination gathers.
// R5-R8 evidence: VGPR-destination gathers are pinned at ~2-3 outstanding
// per wave by the RP-minimizing scheduler (VGPR_Count 16/28/32/40 across 4
// attempts incl. sched_barrier fences); gather phase invariant 42-48us =
// ~640 gather insts/CU x ~180cy (serialized at L2 latency). Fix: issue all
// 40 gathers per wave as global_load_lds (no dest reg, async under vmcnt),
// ONE s_waitcnt vmcnt(0), then ds_read the results back.
// fp16 table kept: gather the aligned dword at (elem>>1)<<2, pick lo/hi by
// elem&1 (slab base l*NEDGES is even). Invalid hops -> dword 0 (hot line).
// ---------------------------------------------------------------------------
__device__ __forceinline__ void issue5(const uint32_t* gdots, uint32_t* lbase,
                                       int len, int i0, int i1, int i2, int i3, int i4) {
  uint32_t e0 = (len > 0) ? (uint32_t)i0 : 0u;
  uint32_t e1 = (len > 1) ? (uint32_t)(1 * NEDGES + i1) : 0u;
  uint32_t e2 = (len > 2) ? (uint32_t)(2 * NEDGES + i2) : 0u;
  uint32_t e3 = (len > 3) ? (uint32_t)(3 * NEDGES + i3) : 0u;
  uint32_t e4 = (len > 4) ? (uint32_t)(4 * NEDGES + i4) : 0u;
  GLL(gdots + (e0 >> 1), lbase + 0 * 64);
  GLL(gdots + (e1 >> 1), lbase + 1 * 64);
  GLL(gdots + (e2 >> 1), lbase + 2 * 64);
  GLL(gdots + (e3 >> 1), lbase + 3 * 64);
  GLL(gdots + (e4 >> 1), lbase + 4 * 64);
}

__device__ __forceinline__ float pick(uint32_t dw, int elem) {
  unsigned short u = (unsigned short)((elem & 1) ? (dw >> 16) : (dw & 0xffffu));
  return __half2float(__ushort_as_half(u));
}

__device__ __forceinline__ float sum5(const uint32_t* lbase, int lane, int len,
                                      int i0, int i1, int i2, int i3, int i4) {
  float v0 = pick(lbase[0 * 64 + lane], i0);
  float v1 = pick(lbase[1 * 64 + lane], i1);
  float v2 = pick(lbase[2 * 64 + lane], i2);
  float v3 = pick(lbase[3 * 64 + lane], i3);
  float v4 = pick(lbase[4 * 64 + lane], i4);
  float s = (((len > 0) ? v0 : 0.f) + ((len > 1) ? v1 : 0.f)) +
            (((len > 2) ? v2 : 0.f) + ((len > 3) ? v3 : 0.f)) +
            ((len > 4) ? v4 : 0.f);
  return s / (float)max(len, 1);  // len==0 -> s==0 -> 0
}

#define NHEAVY 1024  // 512 tiles x 2 half-tiles (32 dst rows x 64 src cols)

__global__ __launch_bounds__(256, 3) void fused_mean_transpose(
    const int* __restrict__ path_idx,
    const int* __restrict__ path_lens,
    const __half* __restrict__ dots,
    float* __restrict__ out) {
  __shared__ float tile[64][33];          // 8448 B
  __shared__ uint32_t gbuf[4][40][64];    // 40960 B (per-wave gather strips)
  const int bid = blockIdx.x;   // 0..NHEAVY-1, consecutive -> XCD-uniform
  const int tid = threadIdx.x;  // 0..255
  const int wave = tid >> 6, lane = tid & 63;

  const int tt = bid >> 1;                 // tile 0..511
  const int h  = bid & 1;                  // half 0..1
  const int dst0 = (tt & 7) * 64 + h * 32; // dst rows 0..511
  const int src0 = (tt >> 3) * 64;
  const uint32_t* gdots = (const uint32_t*)dots;

  {
    const int a = tid >> 4;   // dst row (chunk0) 0..15; chunk1 = a+16
    const int c = tid & 15;   // float4 group along src
    int p0 = (dst0 + a) * NNODES + src0 + 4 * c;   // multiple of 4
    int p1 = p0 + 16 * NNODES;
    float valid0 = (p0 < NPAIRS) ? 1.f : 0.f;
    float valid1 = (p1 < NPAIRS) ? 1.f : 0.f;
    int pc0 = min(p0, NPAIRS - 4);  // NPAIRS%4==0 -> still chunk-aligned
    int pc1 = min(p1, NPAIRS - 4);

    // ---- Phase 1: 12 stream loads (register destinations) ---------------
    const int* q0 = path_idx + (size_t)pc0 * LMAX;  // 16B aligned (pc%4==0)
    const int* q1 = path_idx + (size_t)pc1 * LMAX;
    v4i ln0 = ntload4(path_lens + pc0);
    v4i A0 = ntload4(q0);
    v4i B0 = ntload4(q0 + 4);
    v4i C0 = ntload4(q0 + 8);
    v4i D0 = ntload4(q0 + 12);
    v4i E0 = ntload4(q0 + 16);
    v4i ln1 = ntload4(path_lens + pc1);
    v4i A1 = ntload4(q1);
    v4i B1 = ntload4(q1 + 4);
    v4i C1 = ntload4(q1 + 8);
    v4i D1 = ntload4(q1 + 12);
    v4i E1 = ntload4(q1 + 16);
    __builtin_amdgcn_sched_barrier(0);

    int L0 = min(max(ln0[0], 0), LMAX), L1 = min(max(ln0[1], 0), LMAX);
    int L2 = min(max(ln0[2], 0), LMAX), L3 = min(max(ln0[3], 0), LMAX);
    int L4 = min(max(ln1[0], 0), LMAX), L5 = min(max(ln1[1], 0), LMAX);
    int L6 = min(max(ln1[2], 0), LMAX), L7 = min(max(ln1[3], 0), LMAX);

    // ---- Phase 2: issue all 40 async gathers (no dest regs) -------------
    issue5(gdots, &gbuf[wave][0][0],  L0, A0[0], A0[1], A0[2], A0[3], B0[0]);
    issue5(gdots, &gbuf[wave][5][0],  L1, B0[1], B0[2], B0[3], C0[0], C0[1]);
    issue5(gdots, &gbuf[wave][10][0], L2, C0[2], C0[3], D0[0], D0[1], D0[2]);
    issue5(gdots, &gbuf[wave][15][0], L3, D0[3], E0[0], E0[1], E0[2], E0[3]);
    issue5(gdots, &gbuf[wave][20][0], L4, A1[0], A1[1], A1[2], A1[3], B1[0]);
    issue5(gdots, &gbuf[wave][25][0], L5, B1[1], B1[2], B1[3], C1[0], C1[1]);
    issue5(gdots, &gbuf[wave][30][0], L6, C1[2], C1[3], D1[0], D1[1], D1[2]);
    issue5(gdots, &gbuf[wave][35][0], L7, D1[3], E1[0], E1[1], E1[2], E1[3]);
    asm volatile("s_waitcnt vmcnt(0)" ::: "memory");   // all 40 landed in LDS
    __builtin_amdgcn_sched_barrier(0);

    // ---- Phase 3: ds_read back, select half by parity, mask, sum --------
    float4 v0, v1;
    v0.x = sum5(&gbuf[wave][0][0],  lane, L0, A0[0], A0[1], A0[2], A0[3], B0[0]) * valid0;
    v0.y = sum5(&gbuf[wave][5][0],  lane, L1, B0[1], B0[2], B0[3], C0[0], C0[1]) * valid0;
    v0.z = sum5(&gbuf[wave][10][0], lane, L2, C0[2], C0[3], D0[0], D0[1], D0[2]) * valid0;
    v0.w = sum5(&gbuf[wave][15][0], lane, L3, D0[3], E0[0], E0[1], E0[2], E0[3]) * valid0;
    v1.x = sum5(&gbuf[wave][20][0], lane, L4, A1[0], A1[1], A1[2], A1[3], B1[0]) * valid1;
    v1.y = sum5(&gbuf[wave][25][0], lane, L5, B1[1], B1[2], B1[3], C1[0], C1[1]) * valid1;
    v1.z = sum5(&gbuf[wave][30][0], lane, L6, C1[2], C1[3], D1[0], D1[1], D1[2]) * valid1;
    v1.w = sum5(&gbuf[wave][35][0], lane, L7, D1[3], E1[0], E1[1], E1[2], E1[3]) * valid1;

    tile[4 * c + 0][a] = v0.x;
    tile[4 * c + 1][a] = v0.y;
    tile[4 * c + 2][a] = v0.z;
    tile[4 * c + 3][a] = v0.w;
    tile[4 * c + 0][a + 16] = v1.x;
    tile[4 * c + 1][a + 16] = v1.y;
    tile[4 * c + 2][a + 16] = v1.z;
    tile[4 * c + 3][a + 16] = v1.w;
  }
  __syncthreads();
  {
    const int r  = tid >> 2;  // src row 0..63
    const int cc = tid & 3;   // float4 group along dst (0..3); +16 for second
    float x0 = tile[r][4 * cc + 0];
    float y0 = tile[r][4 * cc + 1];
    float z0 = tile[r][4 * cc + 2];
    float w0 = tile[r][4 * cc + 3];
    float x1 = tile[r][16 + 4 * cc + 0];
    float y1 = tile[r][16 + 4 * cc + 1];
    float z1 = tile[r][16 + 4 * cc + 2];
    float w1 = tile[r][16 + 4 * cc + 3];
    float* o = out + (size_t)(src0 + r) * NNODES + dst0;
    ntstore4(o + 4 * cc, x0, y0, z0, w0);
    ntstore4(o + 16 + 4 * cc, x1, y1, z1, w1);
  }
}

// ---------------------------------------------------------------------------
// Fallback (ws too small): memset + direct fp32 scatter.
// ---------------------------------------------------------------------------
__global__ __launch_bounds__(256) void scatter_kernel(
    const float* __restrict__ edge_attr,
    const float* __restrict__ ew,
    const int* __restrict__ path_idx,
    const int* __restrict__ path_lens,
    float* __restrict__ out) {
  __shared__ float w[LMAX * EDIM];
  if (threadIdx.x < LMAX * EDIM) w[threadIdx.x] = ew[threadIdx.x];
  __syncthreads();

  int p = blockIdx.x * 256 + threadIdx.x;
  if (p >= NPAIRS) return;

  int len = path_lens[p];
  len = min(max(len, 0), LMAX);

  const int* row = path_idx + (size_t)p * LMAX;
  float s = 0.f;
  for (int l = 0; l < len; ++l) {
    int idx = row[l];
    const float4* r = (const float4*)(edge_attr + (size_t)idx * EDIM);
    float4 a0 = r[0], a1 = r[1], a2 = r[2], a3 = r[3];
    const float* wl = &w[l * EDIM];
    s += a0.x * wl[0] + a0.y * wl[1] + a0.z * wl[2] + a0.w * wl[3] +
         a1.x * wl[4] + a1.y * wl[5] + a1.z * wl[6] + a1.w * wl[7] +
         a2.x * wl[8] + a2.y * wl[9] + a2.z * wl[10] + a2.w * wl[11] +
         a3.x * wl[12] + a3.y * wl[13] + a3.z * wl[14] + a3.w * wl[15];
  }
  float m = (len > 0) ? (s / (float)len) : 0.f;
  int src = p & (NNODES - 1);
  int dst = p >> 12;
  out[(size_t)src * NNODES + dst] = m;
}

extern "C" void kernel_launch(void* const* d_in, const int* in_sizes, int n_in,
                              void* d_out, int out_size, void* d_ws, size_t ws_size,
                              hipStream_t stream) {
  // setup_inputs order: x, edge_attr, edge_weights, path_idx, path_lens, pair_id
  const float* edge_attr = (const float*)d_in[1];
  const float* edge_w    = (const float*)d_in[2];
  const int*   path_idx  = (const int*)d_in[3];
  const int*   path_lens = (const int*)d_in[4];
  float* out = (float*)d_out;

  // ws layout: dots fp16 only (5MB).
  const size_t need = (size_t)LMAX * NEDGES * sizeof(__half);

  if (ws_size >= need) {
    __half* dots = (__half*)d_ws;

    // One dispatch: zero the 64MB output (store blocks) || build dots table.
    prep_kernel<<<DBLOCKS + ZBLOCKS, 256, 0, stream>>>(edge_attr, edge_w, dots, out);
    fused_mean_transpose<<<NHEAVY, 256, 0, stream>>>(path_idx, path_lens, dots, out);
  } else {
    hipMemsetAsync(d_out, 0, (size_t)out_size * sizeof(float), stream);
    scatter_kernel<<<(NPAIRS + 255) / 256, 256, 0, stream>>>(
        edge_attr, edge_w, path_idx, path_lens, out);
  }
}

// Round 10
// 174.255 us; speedup vs baseline: 1.0362x; 1.0028x over previous
//
#include <hip/hip_runtime.h>
#include <hip/hip_fp16.h>

#define NNODES 4096
#define NEDGES 500000
#define NPAIRS 2000000
#define EDIM   16
#define LMAX   5

typedef int v4i __attribute__((ext_vector_type(4)));
typedef float v4f __attribute__((ext_vector_type(4)));

__device__ __forceinline__ v4i ntload4(const int* p) {
  return __builtin_nontemporal_load((const v4i*)p);
}
__device__ __forceinline__ void ntstore4(float* p, float x, float y, float z, float w) {
  v4f t = {x, y, z, w};
  __builtin_nontemporal_store(t, (v4f*)p);
}

// Destination-free async gather: per-lane GLOBAL address, LDS dest =
// wave-uniform base + lane*4. Tracked by vmcnt (in-order decrement).
#define GLL(gp, lp) __builtin_amdgcn_global_load_lds(                      \
    (const __attribute__((address_space(1))) uint32_t*)(gp),               \
    (__attribute__((address_space(3))) uint32_t*)(lp), 4, 0, 0)

// ---------------------------------------------------------------------------
// Prep kernel: zero the whole 64MB output (store blocks) AND build the fp16
// dots table (compute blocks) in ONE dispatch.
// ---------------------------------------------------------------------------
#define DBLOCKS ((NEDGES / 2 + 255) / 256)   // 977 dots blocks
#define ZBLOCKS 16384                        // 64MB / (256 thr * 16B)

__global__ __launch_bounds__(256) void prep_kernel(
    const float* __restrict__ edge_attr,
    const float* __restrict__ ew,
    __half* __restrict__ dots,
    float* __restrict__ out) {
  __shared__ float w[LMAX * EDIM];
  const int tid = threadIdx.x, bid = blockIdx.x;

  if (bid >= DBLOCKS) {  // ---- zero block: one float4 per thread
    int z = bid - DBLOCKS;  // 0..ZBLOCKS-1
    ntstore4(out + ((size_t)z * 256 + tid) * 4, 0.f, 0.f, 0.f, 0.f);
    return;
  }

  // ---- dots block
  if (tid < LMAX * EDIM) w[tid] = ew[tid];
  __syncthreads();

  int e0 = (bid * 256 + tid) * 2;  // NEDGES even -> e0+1 always valid
  if (e0 >= NEDGES) return;

  const float4* ra = (const float4*)(edge_attr + (size_t)e0 * EDIM);
  float4 a0 = ra[0], a1 = ra[1], a2 = ra[2], a3 = ra[3];
  float4 b0 = ra[4], b1 = ra[5], b2 = ra[6], b3 = ra[7];  // edge e0+1
  float va[16] = {a0.x, a0.y, a0.z, a0.w, a1.x, a1.y, a1.z, a1.w,
                  a2.x, a2.y, a2.z, a2.w, a3.x, a3.y, a3.z, a3.w};
  float vb[16] = {b0.x, b0.y, b0.z, b0.w, b1.x, b1.y, b1.z, b1.w,
                  b2.x, b2.y, b2.z, b2.w, b3.x, b3.y, b3.z, b3.w};
#pragma unroll
  for (int l = 0; l < LMAX; ++l) {
    float da = 0.f, db = 0.f;
#pragma unroll
    for (int k = 0; k < EDIM; ++k) {
      da += va[k] * w[l * EDIM + k];
      db += vb[k] * w[l * EDIM + k];
    }
    __half2 h;
    h.x = __float2half(da);
    h.y = __float2half(db);
    *(__half2*)(dots + (size_t)l * NEDGES + e0) = h;  // e0 even -> 4B aligned
  }
}

// ---------------------------------------------------------------------------
// Fused mean + transpose, R10: hop-phased gathers (L2-slab residency).
// R9 refuted the "compiler-limited outstanding" hypothesis: 40 async
// LDS-dest gathers in flight per wave, time unchanged. Surviving model:
// per-CU outstanding-miss capacity (~64) x avg latency (~330cy: 88% L2-hit
// against a 5MB table that only marginally fits a 4MB per-XCD L2) pins the
// line-request rate => 48us. Only software lever left: the LATENCY term.
// The table is 5 x 1MB hop-slabs and all 1024 heavy blocks are co-resident
// (4/CU) => phase the gathers hop-by-hop (phase l touches ONLY slab l,
// double-buffered GLL batches, vmcnt(8) pipeline). Device-wide instantaneous
// gather working set ~1-2MB -> slab L2-resident -> latency ~250cy.
// ---------------------------------------------------------------------------
#define NHEAVY 1024  // 512 tiles x 2 half-tiles (32 dst rows x 64 src cols)

__global__ __launch_bounds__(256, 4) void fused_mean_transpose(
    const int* __restrict__ path_idx,
    const int* __restrict__ path_lens,
    const __half* __restrict__ dots,
    float* __restrict__ out) {
  __shared__ float tile[64][33];         // 8448 B
  __shared__ uint32_t gbuf[4][2][8][64]; // 16384 B: [wave][dbuf][pair][lane]
  const int bid = blockIdx.x;   // 0..NHEAVY-1, consecutive -> XCD-uniform
  const int tid = threadIdx.x;  // 0..255
  const int wave = tid >> 6, lane = tid & 63;

  const int tt = bid >> 1;                 // tile 0..511
  const int h  = bid & 1;                  // half 0..1
  const int dst0 = (tt & 7) * 64 + h * 32; // dst rows 0..511
  const int src0 = (tt >> 3) * 64;
  const uint32_t* gdots = (const uint32_t*)dots;

  {
    const int a = tid >> 4;   // dst row (chunk0) 0..15; chunk1 = a+16
    const int c = tid & 15;   // float4 group along src
    int p0 = (dst0 + a) * NNODES + src0 + 4 * c;   // multiple of 4
    int p1 = p0 + 16 * NNODES;
    float valid0 = (p0 < NPAIRS) ? 1.f : 0.f;
    float valid1 = (p1 < NPAIRS) ? 1.f : 0.f;
    int pc0 = min(p0, NPAIRS - 4);  // NPAIRS%4==0 -> still chunk-aligned
    int pc1 = min(p1, NPAIRS - 4);

    // ---- streams: 12 NT dwordx4 ----------------------------------------
    const int* q0 = path_idx + (size_t)pc0 * LMAX;  // 16B aligned (pc%4==0)
    const int* q1 = path_idx + (size_t)pc1 * LMAX;
    v4i ln0 = ntload4(path_lens + pc0);
    v4i A0 = ntload4(q0);
    v4i B0 = ntload4(q0 + 4);
    v4i C0 = ntload4(q0 + 8);
    v4i D0 = ntload4(q0 + 12);
    v4i E0 = ntload4(q0 + 16);
    v4i ln1 = ntload4(path_lens + pc1);
    v4i A1 = ntload4(q1);
    v4i B1 = ntload4(q1 + 4);
    v4i C1 = ntload4(q1 + 8);
    v4i D1 = ntload4(q1 + 12);
    v4i E1 = ntload4(q1 + 16);

    // flat [pair][hop] views, all constant-indexed (stay in regs).
    int f[8][LMAX];
#pragma unroll
    for (int k = 0; k < 4; ++k) {
      f[0][k] = A0[k]; f[4][k] = A1[k];
      f[1][k + 1] = B0[k + 1 > 3 ? 0 : 0], f[1][k] = 0;  // placeholder, filled below
    }
    // explicit fill (pair j, hop l) = flat20[j*5+l]
    f[0][0]=A0[0]; f[0][1]=A0[1]; f[0][2]=A0[2]; f[0][3]=A0[3]; f[0][4]=B0[0];
    f[1][0]=B0[1]; f[1][1]=B0[2]; f[1][2]=B0[3]; f[1][3]=C0[0]; f[1][4]=C0[1];
    f[2][0]=C0[2]; f[2][1]=C0[3]; f[2][2]=D0[0]; f[2][3]=D0[1]; f[2][4]=D0[2];
    f[3][0]=D0[3]; f[3][1]=E0[0]; f[3][2]=E0[1]; f[3][3]=E0[2]; f[3][4]=E0[3];
    f[4][0]=A1[0]; f[4][1]=A1[1]; f[4][2]=A1[2]; f[4][3]=A1[3]; f[4][4]=B1[0];
    f[5][0]=B1[1]; f[5][1]=B1[2]; f[5][2]=B1[3]; f[5][3]=C1[0]; f[5][4]=C1[1];
    f[6][0]=C1[2]; f[6][1]=C1[3]; f[6][2]=D1[0]; f[6][3]=D1[1]; f[6][4]=D1[2];
    f[7][0]=D1[3]; f[7][1]=E1[0]; f[7][2]=E1[1]; f[7][3]=E1[2]; f[7][4]=E1[3];

    int L[8];
    L[0]=min(max(ln0[0],0),LMAX); L[1]=min(max(ln0[1],0),LMAX);
    L[2]=min(max(ln0[2],0),LMAX); L[3]=min(max(ln0[3],0),LMAX);
    L[4]=min(max(ln1[0],0),LMAX); L[5]=min(max(ln1[1],0),LMAX);
    L[6]=min(max(ln1[2],0),LMAX); L[7]=min(max(ln1[3],0),LMAX);

    // Drain streams so vmcnt counts ONLY gather batches from here on.
    asm volatile("s_waitcnt vmcnt(0)" ::: "memory");

    // ---- hop-phased, double-buffered gather pipeline --------------------
    // issue hop 0 into buf 0
#pragma unroll
    for (int j = 0; j < 8; ++j) {
      uint32_t e = (L[j] > 0) ? (uint32_t)f[j][0] : 0u;  // slab0 elem = idx
      GLL(gdots + (e >> 1), &gbuf[wave][0][j][0]);
    }
    float s[8] = {0.f, 0.f, 0.f, 0.f, 0.f, 0.f, 0.f, 0.f};
#pragma unroll
    for (int l = 0; l < LMAX; ++l) {
      if (l + 1 < LMAX) {
#pragma unroll
        for (int j = 0; j < 8; ++j) {
          uint32_t e = (L[j] > l + 1)
              ? (uint32_t)((l + 1) * NEDGES + f[j][l + 1]) : 0u;
          GLL(gdots + (e >> 1), &gbuf[wave][(l + 1) & 1][j][0]);
        }
        asm volatile("s_waitcnt vmcnt(8)" ::: "memory");  // hop l landed
      } else {
        asm volatile("s_waitcnt vmcnt(0)" ::: "memory");  // last hop landed
      }
      __builtin_amdgcn_sched_barrier(0);
#pragma unroll
      for (int j = 0; j < 8; ++j) {
        uint32_t dw = gbuf[wave][l & 1][j][lane];
        unsigned short u = (unsigned short)((f[j][l] & 1) ? (dw >> 16)
                                                          : (dw & 0xffffu));
        float v = __half2float(__ushort_as_half(u));
        s[j] += (L[j] > l) ? v : 0.f;
      }
    }

    float4 v0, v1;
    v0.x = s[0] / (float)max(L[0], 1) * valid0;
    v0.y = s[1] / (float)max(L[1], 1) * valid0;
    v0.z = s[2] / (float)max(L[2], 1) * valid0;
    v0.w = s[3] / (float)max(L[3], 1) * valid0;
    v1.x = s[4] / (float)max(L[4], 1) * valid1;
    v1.y = s[5] / (float)max(L[5], 1) * valid1;
    v1.z = s[6] / (float)max(L[6], 1) * valid1;
    v1.w = s[7] / (float)max(L[7], 1) * valid1;

    tile[4 * c + 0][a] = v0.x;
    tile[4 * c + 1][a] = v0.y;
    tile[4 * c + 2][a] = v0.z;
    tile[4 * c + 3][a] = v0.w;
    tile[4 * c + 0][a + 16] = v1.x;
    tile[4 * c + 1][a + 16] = v1.y;
    tile[4 * c + 2][a + 16] = v1.z;
    tile[4 * c + 3][a + 16] = v1.w;
  }
  __syncthreads();
  {
    const int r  = tid >> 2;  // src row 0..63
    const int cc = tid & 3;   // float4 group along dst (0..3); +16 for second
    float x0 = tile[r][4 * cc + 0];
    float y0 = tile[r][4 * cc + 1];
    float z0 = tile[r][4 * cc + 2];
    float w0 = tile[r][4 * cc + 3];
    float x1 = tile[r][16 + 4 * cc + 0];
    float y1 = tile[r][16 + 4 * cc + 1];
    float z1 = tile[r][16 + 4 * cc + 2];
    float w1 = tile[r][16 + 4 * cc + 3];
    float* o = out + (size_t)(src0 + r) * NNODES + dst0;
    ntstore4(o + 4 * cc, x0, y0, z0, w0);
    ntstore4(o + 16 + 4 * cc, x1, y1, z1, w1);
  }
}

// ---------------------------------------------------------------------------
// Fallback (ws too small): memset + direct fp32 scatter.
// ---------------------------------------------------------------------------
__global__ __launch_bounds__(256) void scatter_kernel(
    const float* __restrict__ edge_attr,
    const float* __restrict__ ew,
    const int* __restrict__ path_idx,
    const int* __restrict__ path_lens,
    float* __restrict__ out) {
  __shared__ float w[LMAX * EDIM];
  if (threadIdx.x < LMAX * EDIM) w[threadIdx.x] = ew[threadIdx.x];
  __syncthreads();

  int p = blockIdx.x * 256 + threadIdx.x;
  if (p >= NPAIRS) return;

  int len = path_lens[p];
  len = min(max(len, 0), LMAX);

  const int* row = path_idx + (size_t)p * LMAX;
  float s = 0.f;
  for (int l = 0; l < len; ++l) {
    int idx = row[l];
    const float4* r = (const float4*)(edge_attr + (size_t)idx * EDIM);
    float4 a0 = r[0], a1 = r[1], a2 = r[2], a3 = r[3];
    const float* wl = &w[l * EDIM];
    s += a0.x * wl[0] + a0.y * wl[1] + a0.z * wl[2] + a0.w * wl[3] +
         a1.x * wl[4] + a1.y * wl[5] + a1.z * wl[6] + a1.w * wl[7] +
         a2.x * wl[8] + a2.y * wl[9] + a2.z * wl[10] + a2.w * wl[11] +
         a3.x * wl[12] + a3.y * wl[13] + a3.z * wl[14] + a3.w * wl[15];
  }
  float m = (len > 0) ? (s / (float)len) : 0.f;
  int src = p & (NNODES - 1);
  int dst = p >> 12;
  out[(size_t)src * NNODES + dst] = m;
}

extern "C" void kernel_launch(void* const* d_in, const int* in_sizes, int n_in,
                              void* d_out, int out_size, void* d_ws, size_t ws_size,
                              hipStream_t stream) {
  // setup_inputs order: x, edge_attr, edge_weights, path_idx, path_lens, pair_id
  const float* edge_attr = (const float*)d_in[1];
  const float* edge_w    = (const float*)d_in[2];
  const int*   path_idx  = (const int*)d_in[3];
  const int*   path_lens = (const int*)d_in[4];
  float* out = (float*)d_out;

  // ws layout: dots fp16 only (5MB).
  const size_t need = (size_t)LMAX * NEDGES * sizeof(__half);

  if (ws_size >= need) {
    __half* dots = (__half*)d_ws;

    // One dispatch: zero the 64MB output (store blocks) || build dots table.
    prep_kernel<<<DBLOCKS + ZBLOCKS, 256, 0, stream>>>(edge_attr, edge_w, dots, out);
    fused_mean_transpose<<<NHEAVY, 256, 0, stream>>>(path_idx, path_lens, dots, out);
  } else {
    hipMemsetAsync(d_out, 0, (size_t)out_size * sizeof(float), stream);
    scatter_kernel<<<(NPAIRS + 255) / 256, 256, 0, stream>>>(
        edge_attr, edge_w, path_idx, path_lens, out);
  }
}